// Round 1
// baseline (239.848 us; speedup 1.0000x reference)
//
#include <hip/hip_runtime.h>
#include <math.h>

namespace {

constexpr int Bn   = 32;
constexpr int Kn   = 32;
constexpr int Fn   = 2048;
constexpr int HIDn = 2;
constexpr int NCLSn = 47;
constexpr float EPSn = 1e-5f;
constexpr int NT = 256;   // threads per block
constexpr int FT = 256;   // LDS tile along the reduced dim

__device__ inline float wave_sum(float v) {
    #pragma unroll
    for (int off = 32; off > 0; off >>= 1) v += __shfl_down(v, off, 64);
    return v;
}

// K1: ysum[b,g] = sum_k neighbor[b,k,0,g]; block 0 also zeroes the BN stats.
__global__ void ysum_kernel(const float* __restrict__ neighbor,
                            float* __restrict__ ysum,
                            double* __restrict__ stats) {
    int idx = blockIdx.x * NT + threadIdx.x;          // over B*F
    if (blockIdx.x == 0 && threadIdx.x < 8) stats[threadIdx.x] = 0.0;
    int b = idx >> 11;
    int g = idx & (Fn - 1);
    const float* p = neighbor + (size_t)b * Kn * Fn + g;
    float s = 0.f;
    #pragma unroll
    for (int k = 0; k < Kn; ++k) s += p[(size_t)k * Fn];
    ysum[idx] = s;
}

// K2: denom[b,g] = sum_f sqrt(|x_f*y_g + x_g*y_f|) + 1e-7 ; store reciprocal
//     and t1[b,c,g] = (w1[c]*x_g + b1[c]) * rden[b,g]
__global__ void denom_kernel(const float* __restrict__ x, const float* __restrict__ ysum,
                             const float* __restrict__ w1, const float* __restrict__ b1,
                             float* __restrict__ rden, float* __restrict__ t1) {
    __shared__ float xs[FT], ys[FT];
    const int b  = blockIdx.x >> 3;                   // F/NT = 8 tiles per b
    const int gt = blockIdx.x & 7;
    const int g  = gt * NT + threadIdx.x;
    const float* xb = x + (size_t)b * Fn;
    const float* yb = ysum + (size_t)b * Fn;
    const float xg = xb[g], yg = yb[g];
    float a0 = 0.f, a1 = 0.f, a2 = 0.f, a3 = 0.f;
    for (int f0 = 0; f0 < Fn; f0 += FT) {
        __syncthreads();
        xs[threadIdx.x] = xb[f0 + threadIdx.x];
        ys[threadIdx.x] = yb[f0 + threadIdx.x];
        __syncthreads();
        #pragma unroll 4
        for (int j = 0; j < FT; j += 4) {
            float v0 = fmaf(xs[j + 0], yg, xg * ys[j + 0]);
            float v1 = fmaf(xs[j + 1], yg, xg * ys[j + 1]);
            float v2 = fmaf(xs[j + 2], yg, xg * ys[j + 2]);
            float v3 = fmaf(xs[j + 3], yg, xg * ys[j + 3]);
            a0 += __builtin_amdgcn_sqrtf(fabsf(v0));
            a1 += __builtin_amdgcn_sqrtf(fabsf(v1));
            a2 += __builtin_amdgcn_sqrtf(fabsf(v2));
            a3 += __builtin_amdgcn_sqrtf(fabsf(v3));
        }
    }
    float den = ((a0 + a1) + (a2 + a3)) + 1e-7f;
    float r = 1.0f / den;
    rden[(size_t)b * Fn + g] = r;
    float h0 = fmaf(w1[0], xg, b1[0]);
    float h1 = fmaf(w1[1], xg, b1[1]);
    t1[((size_t)b * HIDn + 0) * Fn + g] = h0 * r;
    t1[((size_t)b * HIDn + 1) * Fn + g] = h1 * r;
}

// K3/K5: out[b,c,f] = sum_g sgnroot(x_f*y_g + x_g*y_f) * t[b,c,g]
//        plus block-reduced BN statistics (sum, sumsq per channel).
__global__ void matvec_kernel(const float* __restrict__ x, const float* __restrict__ ysum,
                              const float* __restrict__ t, float* __restrict__ out,
                              double* __restrict__ stats) {
    __shared__ float xs[FT], ys[FT], t0s[FT], t1s[FT];
    __shared__ float red[4][4];
    const int b  = blockIdx.x >> 3;
    const int ft = blockIdx.x & 7;
    const int f  = ft * NT + threadIdx.x;
    const float* xb  = x + (size_t)b * Fn;
    const float* yb  = ysum + (size_t)b * Fn;
    const float* t0  = t + (size_t)b * HIDn * Fn;
    const float* t1p = t0 + Fn;
    const float xf = xb[f], yf = yb[f];
    float a0 = 0.f, a1 = 0.f, c0 = 0.f, c1 = 0.f;
    for (int g0 = 0; g0 < Fn; g0 += FT) {
        __syncthreads();
        xs[threadIdx.x]  = xb[g0 + threadIdx.x];
        ys[threadIdx.x]  = yb[g0 + threadIdx.x];
        t0s[threadIdx.x] = t0[g0 + threadIdx.x];
        t1s[threadIdx.x] = t1p[g0 + threadIdx.x];
        __syncthreads();
        #pragma unroll 4
        for (int j = 0; j < FT; j += 2) {
            float v0 = fmaf(xf, ys[j + 0], xs[j + 0] * yf);
            float v1 = fmaf(xf, ys[j + 1], xs[j + 1] * yf);
            float s0 = copysignf(__builtin_amdgcn_sqrtf(fabsf(v0)), v0);
            float s1 = copysignf(__builtin_amdgcn_sqrtf(fabsf(v1)), v1);
            a0 = fmaf(s0, t0s[j + 0], a0);
            a1 = fmaf(s0, t1s[j + 0], a1);
            c0 = fmaf(s1, t0s[j + 1], c0);
            c1 = fmaf(s1, t1s[j + 1], c1);
        }
    }
    float o0 = a0 + c0, o1 = a1 + c1;
    out[((size_t)b * HIDn + 0) * Fn + f] = o0;
    out[((size_t)b * HIDn + 1) * Fn + f] = o1;
    // BN stats: block reduce then one atomic per block
    float s0 = wave_sum(o0);
    float s1 = wave_sum(o1);
    float q0 = wave_sum(o0 * o0);
    float q1 = wave_sum(o1 * o1);
    int wid = threadIdx.x >> 6, lane = threadIdx.x & 63;
    if (lane == 0) { red[wid][0] = s0; red[wid][1] = s1; red[wid][2] = q0; red[wid][3] = q1; }
    __syncthreads();
    if (threadIdx.x == 0) {
        double S0 = 0, S1 = 0, Q0 = 0, Q1 = 0;
        #pragma unroll
        for (int w = 0; w < 4; ++w) {
            S0 += red[w][0]; S1 += red[w][1]; Q0 += red[w][2]; Q1 += red[w][3];
        }
        atomicAdd(&stats[0], S0);
        atomicAdd(&stats[1], S1);
        atomicAdd(&stats[2], Q0);
        atomicAdd(&stats[3], Q1);
    }
}

// K4: BN1 + softsign, then t2[b,c,g] = (sum_i w2[c,i]*z1[b,i,g] + b2[c]) * rden[b,g]
__global__ void bnapply1_kernel(const float* __restrict__ out1, const float* __restrict__ rden,
                                const double* __restrict__ stats,
                                const float* __restrict__ g1, const float* __restrict__ beta1,
                                const float* __restrict__ w2, const float* __restrict__ b2,
                                float* __restrict__ t2) {
    const double N = (double)(Bn * Fn);
    int idx = blockIdx.x * NT + threadIdx.x;          // over B*F
    double m0d = stats[0] / N, m1d = stats[1] / N;
    float mean0 = (float)m0d, mean1 = (float)m1d;
    float var0 = (float)(stats[2] / N - m0d * m0d);
    float var1 = (float)(stats[3] / N - m1d * m1d);
    float inv0 = rsqrtf(var0 + EPSn) * g1[0];
    float inv1 = rsqrtf(var1 + EPSn) * g1[1];
    int b = idx >> 11, g = idx & (Fn - 1);
    size_t base = ((size_t)b * HIDn) * Fn + g;
    float v0 = out1[base], v1 = out1[base + Fn];
    float y0 = fmaf(v0 - mean0, inv0, beta1[0]);
    float y1 = fmaf(v1 - mean1, inv1, beta1[1]);
    float z0 = y0 / (1.f + fabsf(y0));
    float z1 = y1 / (1.f + fabsf(y1));
    float r = rden[idx];
    float h0 = fmaf(w2[0], z0, fmaf(w2[1], z1, b2[0]));
    float h1 = fmaf(w2[2], z0, fmaf(w2[3], z1, b2[1]));
    t2[base] = h0 * r;
    t2[base + Fn] = h1 * r;
}

// K6: BN2 + softsign into LDS, then classifier: out[b,n] = z . Wc[n] + bc[n]
__global__ void final_kernel(const float* __restrict__ out2, const double* __restrict__ stats,
                             const float* __restrict__ g2, const float* __restrict__ beta2,
                             const float* __restrict__ Wc, const float* __restrict__ bc,
                             float* __restrict__ out) {
    __shared__ float z[HIDn * Fn];
    const double N = (double)(Bn * Fn);
    double m0d = stats[0] / N, m1d = stats[1] / N;
    float mean0 = (float)m0d, mean1 = (float)m1d;
    float var0 = (float)(stats[2] / N - m0d * m0d);
    float var1 = (float)(stats[3] / N - m1d * m1d);
    float inv0 = rsqrtf(var0 + EPSn) * g2[0];
    float inv1 = rsqrtf(var1 + EPSn) * g2[1];
    float bet0 = beta2[0], bet1 = beta2[1];
    int b = blockIdx.x;
    const float* src = out2 + (size_t)b * HIDn * Fn;
    for (int i = threadIdx.x; i < HIDn * Fn; i += NT) {
        int c = i >> 11;
        float mc  = c ? mean1 : mean0;
        float ic  = c ? inv1  : inv0;
        float bc2 = c ? bet1  : bet0;
        float v = src[i];
        float y = fmaf(v - mc, ic, bc2);
        z[i] = y / (1.f + fabsf(y));
    }
    __syncthreads();
    int wid = threadIdx.x >> 6, lane = threadIdx.x & 63;
    for (int n = wid; n < NCLSn; n += 4) {
        const float* wn = Wc + (size_t)n * (HIDn * Fn);
        float acc = 0.f;
        for (int i = lane; i < HIDn * Fn; i += 64) acc = fmaf(z[i], wn[i], acc);
        acc = wave_sum(acc);
        if (lane == 0) out[(size_t)b * NCLSn + n] = acc + bc[n];
    }
}

} // namespace

extern "C" void kernel_launch(void* const* d_in, const int* in_sizes, int n_in,
                              void* d_out, int out_size, void* d_ws, size_t ws_size,
                              hipStream_t stream) {
    const float* x        = (const float*)d_in[0];
    const float* neighbor = (const float*)d_in[1];
    const float* w1       = (const float*)d_in[2];
    const float* b1       = (const float*)d_in[3];
    const float* g1       = (const float*)d_in[4];
    const float* beta1    = (const float*)d_in[5];
    const float* w2       = (const float*)d_in[6];
    const float* b2       = (const float*)d_in[7];
    const float* g2       = (const float*)d_in[8];
    const float* beta2    = (const float*)d_in[9];
    const float* Wc       = (const float*)d_in[10];
    const float* bc       = (const float*)d_in[11];
    float* out = (float*)d_out;

    float* ws   = (float*)d_ws;
    float* ysum = ws;                       // B*F
    float* rden = ysum + Bn * Fn;           // B*F
    float* t1   = rden + Bn * Fn;           // B*HID*F
    float* out1 = t1 + Bn * HIDn * Fn;      // B*HID*F
    float* t2   = out1 + Bn * HIDn * Fn;    // B*HID*F
    float* out2 = t2 + Bn * HIDn * Fn;      // B*HID*F
    double* stats = (double*)(out2 + Bn * HIDn * Fn);  // 8 doubles (layer1: 0..3, layer2: 4..7)

    const int grid_bf = (Bn * Fn) / NT;     // 256

    ysum_kernel<<<grid_bf, NT, 0, stream>>>(neighbor, ysum, stats);
    denom_kernel<<<Bn * (Fn / NT), NT, 0, stream>>>(x, ysum, w1, b1, rden, t1);
    matvec_kernel<<<Bn * (Fn / NT), NT, 0, stream>>>(x, ysum, t1, out1, stats);
    bnapply1_kernel<<<grid_bf, NT, 0, stream>>>(out1, rden, stats, g1, beta1, w2, b2, t2);
    matvec_kernel<<<Bn * (Fn / NT), NT, 0, stream>>>(x, ysum, t2, out2, stats + 4);
    final_kernel<<<Bn, NT, 0, stream>>>(out2, stats + 4, g2, beta2, Wc, bc, out);
}

// Round 2
// 165.043 us; speedup vs baseline: 1.4532x; 1.4532x over previous
//
#include <hip/hip_runtime.h>
#include <math.h>

namespace {

constexpr int Bn   = 32;
constexpr int Kn   = 32;
constexpr int Fn   = 2048;
constexpr int HIDn = 2;
constexpr int NCLSn = 47;
constexpr float EPSn = 1e-5f;
constexpr int NT = 256;   // threads per block
constexpr int FT = 256;   // LDS tile along the reduced dim

__device__ inline float wave_sum(float v) {
    #pragma unroll
    for (int off = 32; off > 0; off >>= 1) v += __shfl_down(v, off, 64);
    return v;
}

// K1: ysum[b,g] = sum_k neighbor[b,k,0,g]; block 0 also zeroes the BN stats.
__global__ void ysum_kernel(const float* __restrict__ neighbor,
                            float* __restrict__ ysum,
                            double* __restrict__ stats) {
    int idx = blockIdx.x * NT + threadIdx.x;          // over B*F
    if (blockIdx.x == 0 && threadIdx.x < 8) stats[threadIdx.x] = 0.0;
    int b = idx >> 11;
    int g = idx & (Fn - 1);
    const float* p = neighbor + (size_t)b * Kn * Fn + g;
    float s = 0.f;
    #pragma unroll
    for (int k = 0; k < Kn; ++k) s += p[(size_t)k * Fn];
    ysum[idx] = s;
}

// K2: denom[b,g] = sum_f sqrt(|x_f*y_g + x_g*y_f|) + 1e-7 ; store reciprocal
//     and t1[b,c,g] = (w1[c]*x_g + b1[c]) * rden[b,g]
__global__ void denom_kernel(const float* __restrict__ x, const float* __restrict__ ysum,
                             const float* __restrict__ w1, const float* __restrict__ b1,
                             float* __restrict__ rden, float* __restrict__ t1) {
    __shared__ float xs[FT], ys[FT];
    const int b  = blockIdx.x >> 3;                   // F/NT = 8 tiles per b
    const int gt = blockIdx.x & 7;
    const int g  = gt * NT + threadIdx.x;
    const float* xb = x + (size_t)b * Fn;
    const float* yb = ysum + (size_t)b * Fn;
    const float xg = xb[g], yg = yb[g];
    float a0 = 0.f, a1 = 0.f, a2 = 0.f, a3 = 0.f;
    for (int f0 = 0; f0 < Fn; f0 += FT) {
        __syncthreads();
        xs[threadIdx.x] = xb[f0 + threadIdx.x];
        ys[threadIdx.x] = yb[f0 + threadIdx.x];
        __syncthreads();
        #pragma unroll 4
        for (int j = 0; j < FT; j += 4) {
            float v0 = fmaf(xs[j + 0], yg, xg * ys[j + 0]);
            float v1 = fmaf(xs[j + 1], yg, xg * ys[j + 1]);
            float v2 = fmaf(xs[j + 2], yg, xg * ys[j + 2]);
            float v3 = fmaf(xs[j + 3], yg, xg * ys[j + 3]);
            a0 += __builtin_amdgcn_sqrtf(fabsf(v0));
            a1 += __builtin_amdgcn_sqrtf(fabsf(v1));
            a2 += __builtin_amdgcn_sqrtf(fabsf(v2));
            a3 += __builtin_amdgcn_sqrtf(fabsf(v3));
        }
    }
    float den = ((a0 + a1) + (a2 + a3)) + 1e-7f;
    float r = 1.0f / den;
    rden[(size_t)b * Fn + g] = r;
    float h0 = fmaf(w1[0], xg, b1[0]);
    float h1 = fmaf(w1[1], xg, b1[1]);
    t1[((size_t)b * HIDn + 0) * Fn + g] = h0 * r;
    t1[((size_t)b * HIDn + 1) * Fn + g] = h1 * r;
}

// K3/K5: out[b,c,f] = sum_g sgnroot(x_f*y_g + x_g*y_f) * t[b,c,g]
//        plus block-reduced BN statistics (sum, sumsq per channel).
__global__ void matvec_kernel(const float* __restrict__ x, const float* __restrict__ ysum,
                              const float* __restrict__ t, float* __restrict__ out,
                              double* __restrict__ stats) {
    __shared__ float xs[FT], ys[FT], t0s[FT], t1s[FT];
    __shared__ float red[4][4];
    const int b  = blockIdx.x >> 3;
    const int ft = blockIdx.x & 7;
    const int f  = ft * NT + threadIdx.x;
    const float* xb  = x + (size_t)b * Fn;
    const float* yb  = ysum + (size_t)b * Fn;
    const float* t0  = t + (size_t)b * HIDn * Fn;
    const float* t1p = t0 + Fn;
    const float xf = xb[f], yf = yb[f];
    float a0 = 0.f, a1 = 0.f, c0 = 0.f, c1 = 0.f;
    for (int g0 = 0; g0 < Fn; g0 += FT) {
        __syncthreads();
        xs[threadIdx.x]  = xb[g0 + threadIdx.x];
        ys[threadIdx.x]  = yb[g0 + threadIdx.x];
        t0s[threadIdx.x] = t0[g0 + threadIdx.x];
        t1s[threadIdx.x] = t1p[g0 + threadIdx.x];
        __syncthreads();
        #pragma unroll 4
        for (int j = 0; j < FT; j += 2) {
            float v0 = fmaf(xf, ys[j + 0], xs[j + 0] * yf);
            float v1 = fmaf(xf, ys[j + 1], xs[j + 1] * yf);
            float s0 = copysignf(__builtin_amdgcn_sqrtf(fabsf(v0)), v0);
            float s1 = copysignf(__builtin_amdgcn_sqrtf(fabsf(v1)), v1);
            a0 = fmaf(s0, t0s[j + 0], a0);
            a1 = fmaf(s0, t1s[j + 0], a1);
            c0 = fmaf(s1, t0s[j + 1], c0);
            c1 = fmaf(s1, t1s[j + 1], c1);
        }
    }
    float o0 = a0 + c0, o1 = a1 + c1;
    out[((size_t)b * HIDn + 0) * Fn + f] = o0;
    out[((size_t)b * HIDn + 1) * Fn + f] = o1;
    // BN stats: block reduce then one atomic per block
    float s0 = wave_sum(o0);
    float s1 = wave_sum(o1);
    float q0 = wave_sum(o0 * o0);
    float q1 = wave_sum(o1 * o1);
    int wid = threadIdx.x >> 6, lane = threadIdx.x & 63;
    if (lane == 0) { red[wid][0] = s0; red[wid][1] = s1; red[wid][2] = q0; red[wid][3] = q1; }
    __syncthreads();
    if (threadIdx.x == 0) {
        double S0 = 0, S1 = 0, Q0 = 0, Q1 = 0;
        #pragma unroll
        for (int w = 0; w < 4; ++w) {
            S0 += red[w][0]; S1 += red[w][1]; Q0 += red[w][2]; Q1 += red[w][3];
        }
        atomicAdd(&stats[0], S0);
        atomicAdd(&stats[1], S1);
        atomicAdd(&stats[2], Q0);
        atomicAdd(&stats[3], Q1);
    }
}

// K4: BN1 + softsign, then t2[b,c,g] = (sum_i w2[c,i]*z1[b,i,g] + b2[c]) * rden[b,g]
__global__ void bnapply1_kernel(const float* __restrict__ out1, const float* __restrict__ rden,
                                const double* __restrict__ stats,
                                const float* __restrict__ g1, const float* __restrict__ beta1,
                                const float* __restrict__ w2, const float* __restrict__ b2,
                                float* __restrict__ t2) {
    const double N = (double)(Bn * Fn);
    int idx = blockIdx.x * NT + threadIdx.x;          // over B*F
    double m0d = stats[0] / N, m1d = stats[1] / N;
    float mean0 = (float)m0d, mean1 = (float)m1d;
    float var0 = (float)(stats[2] / N - m0d * m0d);
    float var1 = (float)(stats[3] / N - m1d * m1d);
    float inv0 = rsqrtf(var0 + EPSn) * g1[0];
    float inv1 = rsqrtf(var1 + EPSn) * g1[1];
    int b = idx >> 11, g = idx & (Fn - 1);
    size_t base = ((size_t)b * HIDn) * Fn + g;
    float v0 = out1[base], v1 = out1[base + Fn];
    float y0 = fmaf(v0 - mean0, inv0, beta1[0]);
    float y1 = fmaf(v1 - mean1, inv1, beta1[1]);
    float z0 = y0 / (1.f + fabsf(y0));
    float z1 = y1 / (1.f + fabsf(y1));
    float r = rden[idx];
    float h0 = fmaf(w2[0], z0, fmaf(w2[1], z1, b2[0]));
    float h1 = fmaf(w2[2], z0, fmaf(w2[3], z1, b2[1]));
    t2[base] = h0 * r;
    t2[base + Fn] = h1 * r;
}

// K6: BN2 + softsign elementwise -> z (B, HID, F)
__global__ void bn2z_kernel(const float* __restrict__ out2, const double* __restrict__ stats,
                            const float* __restrict__ g2, const float* __restrict__ beta2,
                            float* __restrict__ z) {
    const double N = (double)(Bn * Fn);
    int idx = blockIdx.x * NT + threadIdx.x;          // over B*F
    double m0d = stats[0] / N, m1d = stats[1] / N;
    float mean0 = (float)m0d, mean1 = (float)m1d;
    float var0 = (float)(stats[2] / N - m0d * m0d);
    float var1 = (float)(stats[3] / N - m1d * m1d);
    float inv0 = rsqrtf(var0 + EPSn) * g2[0];
    float inv1 = rsqrtf(var1 + EPSn) * g2[1];
    int b = idx >> 11, g = idx & (Fn - 1);
    size_t base = ((size_t)b * HIDn) * Fn + g;
    float v0 = out2[base], v1 = out2[base + Fn];
    float y0 = fmaf(v0 - mean0, inv0, beta2[0]);
    float y1 = fmaf(v1 - mean1, inv1, beta2[1]);
    z[base]      = y0 / (1.f + fabsf(y0));
    z[base + Fn] = y1 / (1.f + fabsf(y1));
}

// K7: classifier — one block per (n, b): out[b,n] = z[b,:] . Wc[n,:] + bc[n]
__global__ void classifier_kernel(const float* __restrict__ z, const float* __restrict__ Wc,
                                  const float* __restrict__ bc, float* __restrict__ out) {
    const int n = blockIdx.x;
    const int b = blockIdx.y;
    const float4* z4 = (const float4*)(z + (size_t)b * (HIDn * Fn));
    const float4* w4 = (const float4*)(Wc + (size_t)n * (HIDn * Fn));
    float acc = 0.f;
    #pragma unroll
    for (int it = 0; it < (HIDn * Fn) / (4 * NT); ++it) {
        int i = it * NT + threadIdx.x;
        float4 a = z4[i];
        float4 w = w4[i];
        acc = fmaf(a.x, w.x, acc);
        acc = fmaf(a.y, w.y, acc);
        acc = fmaf(a.z, w.z, acc);
        acc = fmaf(a.w, w.w, acc);
    }
    __shared__ float red[4];
    float s = wave_sum(acc);
    int wid = threadIdx.x >> 6, lane = threadIdx.x & 63;
    if (lane == 0) red[wid] = s;
    __syncthreads();
    if (threadIdx.x == 0) {
        float tot = (red[0] + red[1]) + (red[2] + red[3]);
        out[(size_t)b * NCLSn + n] = tot + bc[n];
    }
}

} // namespace

extern "C" void kernel_launch(void* const* d_in, const int* in_sizes, int n_in,
                              void* d_out, int out_size, void* d_ws, size_t ws_size,
                              hipStream_t stream) {
    const float* x        = (const float*)d_in[0];
    const float* neighbor = (const float*)d_in[1];
    const float* w1       = (const float*)d_in[2];
    const float* b1       = (const float*)d_in[3];
    const float* g1       = (const float*)d_in[4];
    const float* beta1    = (const float*)d_in[5];
    const float* w2       = (const float*)d_in[6];
    const float* b2       = (const float*)d_in[7];
    const float* g2       = (const float*)d_in[8];
    const float* beta2    = (const float*)d_in[9];
    const float* Wc       = (const float*)d_in[10];
    const float* bc       = (const float*)d_in[11];
    float* out = (float*)d_out;

    float* ws   = (float*)d_ws;
    float* ysum = ws;                       // B*F
    float* rden = ysum + Bn * Fn;           // B*F
    float* t1   = rden + Bn * Fn;           // B*HID*F
    float* out1 = t1 + Bn * HIDn * Fn;      // B*HID*F
    float* t2   = out1 + Bn * HIDn * Fn;    // B*HID*F
    float* out2 = t2 + Bn * HIDn * Fn;      // B*HID*F
    float* z    = out2 + Bn * HIDn * Fn;    // B*HID*F
    double* stats = (double*)(z + Bn * HIDn * Fn);  // 8 doubles (layer1: 0..3, layer2: 4..7)

    const int grid_bf = (Bn * Fn) / NT;     // 256

    ysum_kernel<<<grid_bf, NT, 0, stream>>>(neighbor, ysum, stats);
    denom_kernel<<<Bn * (Fn / NT), NT, 0, stream>>>(x, ysum, w1, b1, rden, t1);
    matvec_kernel<<<Bn * (Fn / NT), NT, 0, stream>>>(x, ysum, t1, out1, stats);
    bnapply1_kernel<<<grid_bf, NT, 0, stream>>>(out1, rden, stats, g1, beta1, w2, b2, t2);
    matvec_kernel<<<Bn * (Fn / NT), NT, 0, stream>>>(x, ysum, t2, out2, stats + 4);
    bn2z_kernel<<<grid_bf, NT, 0, stream>>>(out2, stats + 4, g2, beta2, z);
    classifier_kernel<<<dim3(NCLSn, Bn), NT, 0, stream>>>(z, Wc, bc, out);
}

// Round 3
// 122.500 us; speedup vs baseline: 1.9579x; 1.3473x over previous
//
#include <hip/hip_runtime.h>
#include <math.h>

namespace {

constexpr int Bn   = 32;
constexpr int Kn   = 32;
constexpr int Fn   = 2048;
constexpr int HIDn = 2;
constexpr int NCLSn = 47;
constexpr float EPSn = 1e-5f;
constexpr int NT = 256;   // threads per block
constexpr int FT = 256;   // LDS tile along the reduced dim
constexpr int GS = 8;     // split factor along the reduced dim (split-K)
// RF = 2 outputs per thread (register tiling), hard-coded below.

__device__ inline float wave_sum(float v) {
    #pragma unroll
    for (int off = 32; off > 0; off >>= 1) v += __shfl_down(v, off, 64);
    return v;
}

// K1: ysum[b,g] = sum_k neighbor[b,k,0,g]; block 0 also zeroes the BN stats.
__global__ void ysum_kernel(const float* __restrict__ neighbor,
                            float* __restrict__ ysum,
                            double* __restrict__ stats) {
    int idx = blockIdx.x * NT + threadIdx.x;          // over B*F
    if (blockIdx.x == 0 && threadIdx.x < 8) stats[threadIdx.x] = 0.0;
    int b = idx >> 11;
    int g = idx & (Fn - 1);
    const float* p = neighbor + (size_t)b * Kn * Fn + g;
    float s = 0.f;
    #pragma unroll
    for (int k = 0; k < Kn; ++k) s += p[(size_t)k * Fn];
    ysum[idx] = s;
}

// K2: partial denom: dpart[fs][b][g] = sum_{f in slice fs} sqrt(|x_f*y_g + x_g*y_f|)
// grid (Fn/(NT*2), GS, Bn); each thread owns 2 g-outputs.
__global__ void denom_partial_kernel(const float* __restrict__ x, const float* __restrict__ ysum,
                                     float* __restrict__ dpart) {
    __shared__ float xs[FT], ys[FT];
    const int gtile = blockIdx.x;     // 0..3
    const int fs    = blockIdx.y;     // 0..GS-1
    const int b     = blockIdx.z;
    const int tid   = threadIdx.x;
    const float* xb = x + (size_t)b * Fn;
    const float* yb = ysum + (size_t)b * Fn;
    const int f0 = fs * FT;
    xs[tid] = xb[f0 + tid];
    ys[tid] = yb[f0 + tid];
    const int ga = gtile * (NT * 2) + tid;
    const int gb = ga + NT;
    const float xga = xb[ga], yga = yb[ga];
    const float xgb = xb[gb], ygb = yb[gb];
    __syncthreads();
    float da = 0.f, db = 0.f;
    #pragma unroll 8
    for (int j = 0; j < FT; ++j) {
        float xf = xs[j], yf = ys[j];
        float va = fmaf(xf, yga, xga * yf);
        float vb = fmaf(xf, ygb, xgb * yf);
        da += __builtin_amdgcn_sqrtf(fabsf(va));
        db += __builtin_amdgcn_sqrtf(fabsf(vb));
    }
    size_t base = ((size_t)fs * Bn + b) * Fn;
    dpart[base + ga] = da;
    dpart[base + gb] = db;
}

// K3: reduce denom partials -> rden, and t1[b,c,g] = (w1[c]*x_g + b1[c]) * rden
__global__ void denom_reduce_kernel(const float* __restrict__ dpart, const float* __restrict__ x,
                                    const float* __restrict__ w1, const float* __restrict__ b1,
                                    float* __restrict__ rden, float* __restrict__ t1) {
    int idx = blockIdx.x * NT + threadIdx.x;          // over B*F
    const size_t stride = (size_t)Bn * Fn;
    float d = 0.f;
    #pragma unroll
    for (int fs = 0; fs < GS; ++fs) d += dpart[(size_t)fs * stride + idx];
    float r = 1.0f / (d + 1e-7f);
    rden[idx] = r;
    int b = idx >> 11, g = idx & (Fn - 1);
    float xg = x[idx];
    size_t base = ((size_t)b * HIDn) * Fn + g;
    t1[base]      = fmaf(w1[0], xg, b1[0]) * r;
    t1[base + Fn] = fmaf(w1[1], xg, b1[1]) * r;
}

// K4/K7: partial matvec: part[gs][b][c][f] = sum_{g in slice} sgnroot(s(f,g)) * t[b,c,g]
// grid (Fn/(NT*2), GS, Bn); each thread owns 2 f-outputs, both channels.
__global__ void matvec_partial_kernel(const float* __restrict__ x, const float* __restrict__ ysum,
                                      const float* __restrict__ t, float* __restrict__ part) {
    __shared__ float xs[FT], ys[FT], t0s[FT], t1s[FT];
    const int ftile = blockIdx.x;     // 0..3
    const int gs    = blockIdx.y;     // 0..GS-1
    const int b     = blockIdx.z;
    const int tid   = threadIdx.x;
    const float* xb = x + (size_t)b * Fn;
    const float* yb = ysum + (size_t)b * Fn;
    const float* tb = t + (size_t)b * HIDn * Fn;
    const int g0 = gs * FT;
    xs[tid]  = xb[g0 + tid];
    ys[tid]  = yb[g0 + tid];
    t0s[tid] = tb[g0 + tid];
    t1s[tid] = tb[Fn + g0 + tid];
    const int fa = ftile * (NT * 2) + tid;
    const int fb = fa + NT;
    const float xfa = xb[fa], yfa = yb[fa];
    const float xfb = xb[fb], yfb = yb[fb];
    __syncthreads();
    float a0 = 0.f, a1 = 0.f, c0 = 0.f, c1 = 0.f;
    #pragma unroll 8
    for (int j = 0; j < FT; ++j) {
        float xg = xs[j], yg = ys[j], u0 = t0s[j], u1 = t1s[j];
        float va = fmaf(xfa, yg, xg * yfa);
        float vb = fmaf(xfb, yg, xg * yfb);
        float sa = copysignf(__builtin_amdgcn_sqrtf(fabsf(va)), va);
        float sb = copysignf(__builtin_amdgcn_sqrtf(fabsf(vb)), vb);
        a0 = fmaf(sa, u0, a0);
        a1 = fmaf(sa, u1, a1);
        c0 = fmaf(sb, u0, c0);
        c1 = fmaf(sb, u1, c1);
    }
    size_t base = (((size_t)gs * Bn + b) * HIDn) * Fn;
    part[base + fa]      = a0;
    part[base + Fn + fa] = a1;
    part[base + fb]      = c0;
    part[base + Fn + fb] = c1;
}

// K5/K8: reduce matvec partials -> out[b,c,f], plus BN statistics.
__global__ void matvec_reduce_kernel(const float* __restrict__ part, float* __restrict__ out,
                                     double* __restrict__ stats) {
    __shared__ float red[4][4];
    int idx = blockIdx.x * NT + threadIdx.x;          // over B*F
    int b = idx >> 11, f = idx & (Fn - 1);
    const size_t stride = (size_t)Bn * HIDn * Fn;
    size_t base = ((size_t)b * HIDn) * Fn + f;
    float o0 = 0.f, o1 = 0.f;
    #pragma unroll
    for (int gs = 0; gs < GS; ++gs) {
        o0 += part[(size_t)gs * stride + base];
        o1 += part[(size_t)gs * stride + base + Fn];
    }
    out[base]      = o0;
    out[base + Fn] = o1;
    float s0 = wave_sum(o0);
    float s1 = wave_sum(o1);
    float q0 = wave_sum(o0 * o0);
    float q1 = wave_sum(o1 * o1);
    int wid = threadIdx.x >> 6, lane = threadIdx.x & 63;
    if (lane == 0) { red[wid][0] = s0; red[wid][1] = s1; red[wid][2] = q0; red[wid][3] = q1; }
    __syncthreads();
    if (threadIdx.x == 0) {
        double S0 = 0, S1 = 0, Q0 = 0, Q1 = 0;
        #pragma unroll
        for (int w = 0; w < 4; ++w) {
            S0 += red[w][0]; S1 += red[w][1]; Q0 += red[w][2]; Q1 += red[w][3];
        }
        atomicAdd(&stats[0], S0);
        atomicAdd(&stats[1], S1);
        atomicAdd(&stats[2], Q0);
        atomicAdd(&stats[3], Q1);
    }
}

// K6: BN1 + softsign, then t2[b,c,g] = (sum_i w2[c,i]*z1[b,i,g] + b2[c]) * rden[b,g]
__global__ void bnapply1_kernel(const float* __restrict__ out1, const float* __restrict__ rden,
                                const double* __restrict__ stats,
                                const float* __restrict__ g1, const float* __restrict__ beta1,
                                const float* __restrict__ w2, const float* __restrict__ b2,
                                float* __restrict__ t2) {
    const double N = (double)(Bn * Fn);
    int idx = blockIdx.x * NT + threadIdx.x;          // over B*F
    double m0d = stats[0] / N, m1d = stats[1] / N;
    float mean0 = (float)m0d, mean1 = (float)m1d;
    float var0 = (float)(stats[2] / N - m0d * m0d);
    float var1 = (float)(stats[3] / N - m1d * m1d);
    float inv0 = rsqrtf(var0 + EPSn) * g1[0];
    float inv1 = rsqrtf(var1 + EPSn) * g1[1];
    int b = idx >> 11, g = idx & (Fn - 1);
    size_t base = ((size_t)b * HIDn) * Fn + g;
    float v0 = out1[base], v1 = out1[base + Fn];
    float y0 = fmaf(v0 - mean0, inv0, beta1[0]);
    float y1 = fmaf(v1 - mean1, inv1, beta1[1]);
    float z0 = y0 / (1.f + fabsf(y0));
    float z1 = y1 / (1.f + fabsf(y1));
    float r = rden[idx];
    float h0 = fmaf(w2[0], z0, fmaf(w2[1], z1, b2[0]));
    float h1 = fmaf(w2[2], z0, fmaf(w2[3], z1, b2[1]));
    t2[base] = h0 * r;
    t2[base + Fn] = h1 * r;
}

// K9: BN2 + softsign elementwise -> z (B, HID, F)
__global__ void bn2z_kernel(const float* __restrict__ out2, const double* __restrict__ stats,
                            const float* __restrict__ g2, const float* __restrict__ beta2,
                            float* __restrict__ z) {
    const double N = (double)(Bn * Fn);
    int idx = blockIdx.x * NT + threadIdx.x;          // over B*F
    double m0d = stats[0] / N, m1d = stats[1] / N;
    float mean0 = (float)m0d, mean1 = (float)m1d;
    float var0 = (float)(stats[2] / N - m0d * m0d);
    float var1 = (float)(stats[3] / N - m1d * m1d);
    float inv0 = rsqrtf(var0 + EPSn) * g2[0];
    float inv1 = rsqrtf(var1 + EPSn) * g2[1];
    int b = idx >> 11, g = idx & (Fn - 1);
    size_t base = ((size_t)b * HIDn) * Fn + g;
    float v0 = out2[base], v1 = out2[base + Fn];
    float y0 = fmaf(v0 - mean0, inv0, beta2[0]);
    float y1 = fmaf(v1 - mean1, inv1, beta2[1]);
    z[base]      = y0 / (1.f + fabsf(y0));
    z[base + Fn] = y1 / (1.f + fabsf(y1));
}

// K10: classifier — one block per (n, b): out[b,n] = z[b,:] . Wc[n,:] + bc[n]
__global__ void classifier_kernel(const float* __restrict__ z, const float* __restrict__ Wc,
                                  const float* __restrict__ bc, float* __restrict__ out) {
    const int n = blockIdx.x;
    const int b = blockIdx.y;
    const float4* z4 = (const float4*)(z + (size_t)b * (HIDn * Fn));
    const float4* w4 = (const float4*)(Wc + (size_t)n * (HIDn * Fn));
    float acc = 0.f;
    #pragma unroll
    for (int it = 0; it < (HIDn * Fn) / (4 * NT); ++it) {
        int i = it * NT + threadIdx.x;
        float4 a = z4[i];
        float4 w = w4[i];
        acc = fmaf(a.x, w.x, acc);
        acc = fmaf(a.y, w.y, acc);
        acc = fmaf(a.z, w.z, acc);
        acc = fmaf(a.w, w.w, acc);
    }
    __shared__ float red[4];
    float s = wave_sum(acc);
    int wid = threadIdx.x >> 6, lane = threadIdx.x & 63;
    if (lane == 0) red[wid] = s;
    __syncthreads();
    if (threadIdx.x == 0) {
        float tot = (red[0] + red[1]) + (red[2] + red[3]);
        out[(size_t)b * NCLSn + n] = tot + bc[n];
    }
}

} // namespace

extern "C" void kernel_launch(void* const* d_in, const int* in_sizes, int n_in,
                              void* d_out, int out_size, void* d_ws, size_t ws_size,
                              hipStream_t stream) {
    const float* x        = (const float*)d_in[0];
    const float* neighbor = (const float*)d_in[1];
    const float* w1       = (const float*)d_in[2];
    const float* b1       = (const float*)d_in[3];
    const float* g1       = (const float*)d_in[4];
    const float* beta1    = (const float*)d_in[5];
    const float* w2       = (const float*)d_in[6];
    const float* b2       = (const float*)d_in[7];
    const float* g2       = (const float*)d_in[8];
    const float* beta2    = (const float*)d_in[9];
    const float* Wc       = (const float*)d_in[10];
    const float* bc       = (const float*)d_in[11];
    float* out = (float*)d_out;

    float* ws   = (float*)d_ws;
    float* ysum = ws;                       // B*F
    float* rden = ysum + Bn * Fn;           // B*F
    float* t1   = rden + Bn * Fn;           // B*HID*F
    float* out1 = t1 + Bn * HIDn * Fn;      // B*HID*F
    float* t2   = out1 + Bn * HIDn * Fn;    // B*HID*F
    float* out2 = t2 + Bn * HIDn * Fn;      // B*HID*F
    float* z    = out2 + Bn * HIDn * Fn;    // B*HID*F
    float* part = z + Bn * HIDn * Fn;       // GS*B*HID*F (shared: dpart uses first GS*B*F)
    double* stats = (double*)(part + (size_t)GS * Bn * HIDn * Fn);  // 8 doubles

    const int grid_bf = (Bn * Fn) / NT;     // 256
    const dim3 grid_split(Fn / (NT * 2), GS, Bn);  // (4, 8, 32) = 1024 blocks

    ysum_kernel<<<grid_bf, NT, 0, stream>>>(neighbor, ysum, stats);
    denom_partial_kernel<<<grid_split, NT, 0, stream>>>(x, ysum, part);
    denom_reduce_kernel<<<grid_bf, NT, 0, stream>>>(part, x, w1, b1, rden, t1);
    matvec_partial_kernel<<<grid_split, NT, 0, stream>>>(x, ysum, t1, part);
    matvec_reduce_kernel<<<grid_bf, NT, 0, stream>>>(part, out1, stats);
    bnapply1_kernel<<<grid_bf, NT, 0, stream>>>(out1, rden, stats, g1, beta1, w2, b2, t2);
    matvec_partial_kernel<<<grid_split, NT, 0, stream>>>(x, ysum, t2, part);
    matvec_reduce_kernel<<<grid_bf, NT, 0, stream>>>(part, out2, stats + 4);
    bn2z_kernel<<<grid_bf, NT, 0, stream>>>(out2, stats + 4, g2, beta2, z);
    classifier_kernel<<<dim3(NCLSn, Bn), NT, 0, stream>>>(z, Wc, bc, out);
}

// Round 4
// 122.156 us; speedup vs baseline: 1.9635x; 1.0028x over previous
//
#include <hip/hip_runtime.h>
#include <math.h>

namespace {

constexpr int Bn   = 32;
constexpr int Kn   = 32;
constexpr int Fn   = 2048;
constexpr int HIDn = 2;
constexpr int NCLSn = 47;
constexpr float EPSn = 1e-5f;
constexpr int NT = 256;   // threads per block
constexpr int GS = 16;    // split factor along the reduced dim
constexpr int FT = Fn / GS;  // 128: LDS tile = one slice, single sync per block

__device__ inline float wave_sum(float v) {
    #pragma unroll
    for (int off = 32; off > 0; off >>= 1) v += __shfl_down(v, off, 64);
    return v;
}

// K1: ysum[b,g] = sum_k neighbor[b,k,0,g]; block 0 also zeroes the BN stats.
__global__ void ysum_kernel(const float* __restrict__ neighbor,
                            float* __restrict__ ysum,
                            double* __restrict__ stats) {
    int idx = blockIdx.x * NT + threadIdx.x;          // over B*F
    if (blockIdx.x == 0 && threadIdx.x < 8) stats[threadIdx.x] = 0.0;
    int b = idx >> 11;
    int g = idx & (Fn - 1);
    const float* p = neighbor + (size_t)b * Kn * Fn + g;
    float s = 0.f;
    #pragma unroll
    for (int k = 0; k < Kn; ++k) s += p[(size_t)k * Fn];
    ysum[idx] = s;
}

// K2: partial denom: dpart[fs][b][g] = sum_{f in slice fs} sqrt(|x_f*y_g + x_g*y_f|)
// grid (Fn/(NT*2), GS, Bn) = (4, 16, 32); each thread owns 2 g-outputs.
__global__ void denom_partial_kernel(const float* __restrict__ x, const float* __restrict__ ysum,
                                     float* __restrict__ dpart) {
    __shared__ float2 xy[FT];
    const int gtile = blockIdx.x;
    const int fs    = blockIdx.y;
    const int b     = blockIdx.z;
    const int tid   = threadIdx.x;
    const float* xb = x + (size_t)b * Fn;
    const float* yb = ysum + (size_t)b * Fn;
    if (tid < FT) {
        int f = fs * FT + tid;
        xy[tid] = make_float2(xb[f], yb[f]);
    }
    const int ga = gtile * (NT * 2) + tid;
    const int gb = ga + NT;
    const float xga = xb[ga], yga = yb[ga];
    const float xgb = xb[gb], ygb = yb[gb];
    __syncthreads();
    float da = 0.f, db = 0.f;
    #pragma unroll 8
    for (int j = 0; j < FT; ++j) {
        float xf = xy[j].x, yf = xy[j].y;
        float va = fmaf(xf, yga, xga * yf);
        float vb = fmaf(xf, ygb, xgb * yf);
        da += __builtin_amdgcn_sqrtf(fabsf(va));
        db += __builtin_amdgcn_sqrtf(fabsf(vb));
    }
    size_t base = ((size_t)fs * Bn + b) * Fn;
    dpart[base + ga] = da;
    dpart[base + gb] = db;
}

// K3: reduce denom partials -> rden, and t1[b,c,g] = (w1[c]*x_g + b1[c]) * rden
__global__ void denom_reduce_kernel(const float* __restrict__ dpart, const float* __restrict__ x,
                                    const float* __restrict__ w1, const float* __restrict__ b1,
                                    float* __restrict__ rden, float* __restrict__ t1) {
    int idx = blockIdx.x * NT + threadIdx.x;          // over B*F
    const size_t stride = (size_t)Bn * Fn;
    float d = 0.f;
    #pragma unroll
    for (int fs = 0; fs < GS; ++fs) d += dpart[(size_t)fs * stride + idx];
    float r = 1.0f / (d + 1e-7f);
    rden[idx] = r;
    int b = idx >> 11, g = idx & (Fn - 1);
    float xg = x[idx];
    size_t base = ((size_t)b * HIDn) * Fn + g;
    t1[base]      = fmaf(w1[0], xg, b1[0]) * r;
    t1[base + Fn] = fmaf(w1[1], xg, b1[1]) * r;
}

// K4/K7: partial matvec: part[gs][b][c][f] = sum_{g in slice} sgnroot(s(f,g)) * t[b,c,g]
// grid (4, GS, Bn); each thread owns 2 f-outputs, both channels.
__global__ void matvec_partial_kernel(const float* __restrict__ x, const float* __restrict__ ysum,
                                      const float* __restrict__ t, float* __restrict__ part) {
    __shared__ float2 xy[FT];
    __shared__ float2 ts[FT];
    const int ftile = blockIdx.x;
    const int gs    = blockIdx.y;
    const int b     = blockIdx.z;
    const int tid   = threadIdx.x;
    const float* xb = x + (size_t)b * Fn;
    const float* yb = ysum + (size_t)b * Fn;
    const float* tb = t + (size_t)b * HIDn * Fn;
    if (tid < FT) {
        int g = gs * FT + tid;
        xy[tid] = make_float2(xb[g], yb[g]);
        ts[tid] = make_float2(tb[g], tb[Fn + g]);
    }
    const int fa = ftile * (NT * 2) + tid;
    const int fb = fa + NT;
    const float xfa = xb[fa], yfa = yb[fa];
    const float xfb = xb[fb], yfb = yb[fb];
    __syncthreads();
    float a0 = 0.f, a1 = 0.f, c0 = 0.f, c1 = 0.f;
    #pragma unroll 8
    for (int j = 0; j < FT; ++j) {
        float xg = xy[j].x, yg = xy[j].y;
        float2 u = ts[j];
        float va = fmaf(xfa, yg, xg * yfa);
        float vb = fmaf(xfb, yg, xg * yfb);
        float sa = copysignf(__builtin_amdgcn_sqrtf(fabsf(va)), va);
        float sb = copysignf(__builtin_amdgcn_sqrtf(fabsf(vb)), vb);
        a0 = fmaf(sa, u.x, a0);
        a1 = fmaf(sa, u.y, a1);
        c0 = fmaf(sb, u.x, c0);
        c1 = fmaf(sb, u.y, c1);
    }
    size_t base = (((size_t)gs * Bn + b) * HIDn) * Fn;
    part[base + fa]      = a0;
    part[base + Fn + fa] = a1;
    part[base + fb]      = c0;
    part[base + Fn + fb] = c1;
}

// K5/K8: reduce matvec partials -> out[b,c,f], plus BN statistics.
__global__ void matvec_reduce_kernel(const float* __restrict__ part, float* __restrict__ out,
                                     double* __restrict__ stats) {
    __shared__ float red[4][4];
    int idx = blockIdx.x * NT + threadIdx.x;          // over B*F
    int b = idx >> 11, f = idx & (Fn - 1);
    const size_t stride = (size_t)Bn * HIDn * Fn;
    size_t base = ((size_t)b * HIDn) * Fn + f;
    float o0 = 0.f, o1 = 0.f;
    #pragma unroll
    for (int gs = 0; gs < GS; ++gs) {
        o0 += part[(size_t)gs * stride + base];
        o1 += part[(size_t)gs * stride + base + Fn];
    }
    out[base]      = o0;
    out[base + Fn] = o1;
    float s0 = wave_sum(o0);
    float s1 = wave_sum(o1);
    float q0 = wave_sum(o0 * o0);
    float q1 = wave_sum(o1 * o1);
    int wid = threadIdx.x >> 6, lane = threadIdx.x & 63;
    if (lane == 0) { red[wid][0] = s0; red[wid][1] = s1; red[wid][2] = q0; red[wid][3] = q1; }
    __syncthreads();
    if (threadIdx.x == 0) {
        double S0 = 0, S1 = 0, Q0 = 0, Q1 = 0;
        #pragma unroll
        for (int w = 0; w < 4; ++w) {
            S0 += red[w][0]; S1 += red[w][1]; Q0 += red[w][2]; Q1 += red[w][3];
        }
        atomicAdd(&stats[0], S0);
        atomicAdd(&stats[1], S1);
        atomicAdd(&stats[2], Q0);
        atomicAdd(&stats[3], Q1);
    }
}

// K6: BN1 + softsign, then t2[b,c,g] = (sum_i w2[c,i]*z1[b,i,g] + b2[c]) * rden[b,g]
__global__ void bnapply1_kernel(const float* __restrict__ out1, const float* __restrict__ rden,
                                const double* __restrict__ stats,
                                const float* __restrict__ g1, const float* __restrict__ beta1,
                                const float* __restrict__ w2, const float* __restrict__ b2,
                                float* __restrict__ t2) {
    const double N = (double)(Bn * Fn);
    int idx = blockIdx.x * NT + threadIdx.x;          // over B*F
    double m0d = stats[0] / N, m1d = stats[1] / N;
    float mean0 = (float)m0d, mean1 = (float)m1d;
    float var0 = (float)(stats[2] / N - m0d * m0d);
    float var1 = (float)(stats[3] / N - m1d * m1d);
    float inv0 = rsqrtf(var0 + EPSn) * g1[0];
    float inv1 = rsqrtf(var1 + EPSn) * g1[1];
    int b = idx >> 11, g = idx & (Fn - 1);
    size_t base = ((size_t)b * HIDn) * Fn + g;
    float v0 = out1[base], v1 = out1[base + Fn];
    float y0 = fmaf(v0 - mean0, inv0, beta1[0]);
    float y1 = fmaf(v1 - mean1, inv1, beta1[1]);
    float z0 = y0 / (1.f + fabsf(y0));
    float z1 = y1 / (1.f + fabsf(y1));
    float r = rden[idx];
    float h0 = fmaf(w2[0], z0, fmaf(w2[1], z1, b2[0]));
    float h1 = fmaf(w2[2], z0, fmaf(w2[3], z1, b2[1]));
    t2[base] = h0 * r;
    t2[base + Fn] = h1 * r;
}

// K9: fused BN2 + softsign (into LDS) + classifier.
// grid (NCLS, B): out[b,n] = softsign(bn2(out2[b,:])) . Wc[n,:] + bc[n]
__global__ void classifier_kernel(const float* __restrict__ out2, const double* __restrict__ stats,
                                  const float* __restrict__ g2, const float* __restrict__ beta2,
                                  const float* __restrict__ Wc, const float* __restrict__ bc,
                                  float* __restrict__ out) {
    __shared__ float z[HIDn * Fn];  // 16 KiB
    const int n = blockIdx.x;
    const int b = blockIdx.y;
    const double N = (double)(Bn * Fn);
    double m0d = stats[0] / N, m1d = stats[1] / N;
    float mean0 = (float)m0d, mean1 = (float)m1d;
    float var0 = (float)(stats[2] / N - m0d * m0d);
    float var1 = (float)(stats[3] / N - m1d * m1d);
    float inv0 = rsqrtf(var0 + EPSn) * g2[0];
    float inv1 = rsqrtf(var1 + EPSn) * g2[1];
    float bet0 = beta2[0], bet1 = beta2[1];
    const float* src = out2 + (size_t)b * HIDn * Fn;
    #pragma unroll
    for (int it = 0; it < (HIDn * Fn) / NT; ++it) {
        int i = it * NT + threadIdx.x;
        int c = i >> 11;
        float v = src[i];
        float y = fmaf(v - (c ? mean1 : mean0), (c ? inv1 : inv0), (c ? bet1 : bet0));
        z[i] = y / (1.f + fabsf(y));
    }
    __syncthreads();
    const float4* z4 = (const float4*)z;
    const float4* w4 = (const float4*)(Wc + (size_t)n * (HIDn * Fn));
    float acc = 0.f;
    #pragma unroll
    for (int it = 0; it < (HIDn * Fn) / (4 * NT); ++it) {
        int i = it * NT + threadIdx.x;
        float4 a = z4[i];
        float4 w = w4[i];
        acc = fmaf(a.x, w.x, acc);
        acc = fmaf(a.y, w.y, acc);
        acc = fmaf(a.z, w.z, acc);
        acc = fmaf(a.w, w.w, acc);
    }
    __shared__ float red[4];
    float s = wave_sum(acc);
    int wid = threadIdx.x >> 6, lane = threadIdx.x & 63;
    if (lane == 0) red[wid] = s;
    __syncthreads();
    if (threadIdx.x == 0) {
        float tot = (red[0] + red[1]) + (red[2] + red[3]);
        out[(size_t)b * NCLSn + n] = tot + bc[n];
    }
}

} // namespace

extern "C" void kernel_launch(void* const* d_in, const int* in_sizes, int n_in,
                              void* d_out, int out_size, void* d_ws, size_t ws_size,
                              hipStream_t stream) {
    const float* x        = (const float*)d_in[0];
    const float* neighbor = (const float*)d_in[1];
    const float* w1       = (const float*)d_in[2];
    const float* b1       = (const float*)d_in[3];
    const float* g1       = (const float*)d_in[4];
    const float* beta1    = (const float*)d_in[5];
    const float* w2       = (const float*)d_in[6];
    const float* b2       = (const float*)d_in[7];
    const float* g2       = (const float*)d_in[8];
    const float* beta2    = (const float*)d_in[9];
    const float* Wc       = (const float*)d_in[10];
    const float* bc       = (const float*)d_in[11];
    float* out = (float*)d_out;

    float* ws   = (float*)d_ws;
    float* ysum = ws;                       // B*F
    float* rden = ysum + Bn * Fn;           // B*F
    float* t1   = rden + Bn * Fn;           // B*HID*F
    float* out1 = t1 + Bn * HIDn * Fn;      // B*HID*F
    float* t2   = out1 + Bn * HIDn * Fn;    // B*HID*F
    float* out2 = t2 + Bn * HIDn * Fn;      // B*HID*F
    float* part = out2 + Bn * HIDn * Fn;    // GS*B*HID*F (dpart uses first GS*B*F)
    double* stats = (double*)(part + (size_t)GS * Bn * HIDn * Fn);  // 8 doubles

    const int grid_bf = (Bn * Fn) / NT;     // 256
    const dim3 grid_split(Fn / (NT * 2), GS, Bn);  // (4, 16, 32) = 2048 blocks

    ysum_kernel<<<grid_bf, NT, 0, stream>>>(neighbor, ysum, stats);
    denom_partial_kernel<<<grid_split, NT, 0, stream>>>(x, ysum, part);
    denom_reduce_kernel<<<grid_bf, NT, 0, stream>>>(part, x, w1, b1, rden, t1);
    matvec_partial_kernel<<<grid_split, NT, 0, stream>>>(x, ysum, t1, part);
    matvec_reduce_kernel<<<grid_bf, NT, 0, stream>>>(part, out1, stats);
    bnapply1_kernel<<<grid_bf, NT, 0, stream>>>(out1, rden, stats, g1, beta1, w2, b2, t2);
    matvec_partial_kernel<<<grid_split, NT, 0, stream>>>(x, ysum, t2, part);
    matvec_reduce_kernel<<<grid_bf, NT, 0, stream>>>(part, out2, stats + 4);
    classifier_kernel<<<dim3(NCLSn, Bn), NT, 0, stream>>>(out2, stats + 4, g2, beta2, Wc, bc, out);
}

// Round 6
// 100.129 us; speedup vs baseline: 2.3954x; 1.2200x over previous
//
#include <hip/hip_runtime.h>
#include <math.h>

namespace {

constexpr int Bn   = 32;
constexpr int Kn   = 32;
constexpr int Fn   = 2048;
constexpr int HIDn = 2;
constexpr int NCLSn = 47;
constexpr float EPSn = 1e-5f;
constexpr int NT = 256;     // threads per block
constexpr int GS = 8;       // split factor along the reduced dim
constexpr int FT = 256;     // LDS tile along the reduced dim (= NT)

typedef float v2f __attribute__((ext_vector_type(2)));

__device__ inline float wave_sum(float v) {
    #pragma unroll
    for (int off = 32; off > 0; off >>= 1) v += __shfl_down(v, off, 64);
    return v;
}

// ---------------------------------------------------------------------------
// K1: ysum[b,g] = sum_k neighbor[b,k,0,g]; block 0 also zeroes the BN stats.
__global__ void ysum_kernel(const float* __restrict__ neighbor,
                            float* __restrict__ ysum,
                            double* __restrict__ stats) {
    int idx = blockIdx.x * NT + threadIdx.x;          // over B*F
    if (blockIdx.x == 0 && threadIdx.x < 8) stats[threadIdx.x] = 0.0;
    int b = idx >> 11;
    int g = idx & (Fn - 1);
    const float* p = neighbor + (size_t)b * Kn * Fn + g;
    float s = 0.f;
    #pragma unroll
    for (int k = 0; k < Kn; ++k) s += p[(size_t)k * Fn];
    ysum[idx] = s;
}

// ---------------------------------------------------------------------------
// K2: partial denom: dpart[fs][b][g] = sum_{f in slice fs} sqrt(|x_f*y_g + x_g*y_f|)
// grid (Fn/(NT*2), GS, Bn) = (4, 8, 32); each thread owns 2 ADJACENT g.
// LDS holds per-f duplicated pairs so the inner loop is pure packed fp32.
__global__ void denom_partial_kernel(const float* __restrict__ x, const float* __restrict__ ysum,
                                     float* __restrict__ dpart) {
    __shared__ v2f xf2[FT], yf2[FT];                  // (x_f,x_f), (y_f,y_f)
    const int gtile = blockIdx.x;
    const int fs    = blockIdx.y;
    const int b     = blockIdx.z;
    const int tid   = threadIdx.x;
    const float* xb = x + (size_t)b * Fn;
    const float* yb = ysum + (size_t)b * Fn;
    {
        int f = fs * FT + tid;
        float xv = xb[f], yv = yb[f];
        xf2[tid] = (v2f){xv, xv};
        yf2[tid] = (v2f){yv, yv};
    }
    const int gbase = (gtile * NT + tid) * 2;         // adjacent pair
    const v2f Xg2 = *(const v2f*)(xb + gbase);
    const v2f Yg2 = *(const v2f*)(yb + gbase);
    __syncthreads();
    v2f dacc = (v2f){0.f, 0.f};
    #pragma unroll 8
    for (int j = 0; j < FT; ++j) {
        v2f v = Xg2 * yf2[j] + Yg2 * xf2[j];          // s(f, g-pair)
        v2f s2;
        s2.x = __builtin_amdgcn_sqrtf(fabsf(v.x));
        s2.y = __builtin_amdgcn_sqrtf(fabsf(v.y));
        dacc += s2;
    }
    size_t base = ((size_t)fs * Bn + b) * Fn;
    *(v2f*)(dpart + base + gbase) = dacc;
}

// ---------------------------------------------------------------------------
// Shared packed inner loop: thread owns adjacent f-pair, accumulates both channels.
__device__ inline void mv_loop(const v2f* __restrict__ xg2, const v2f* __restrict__ yg2,
                               const v2f* __restrict__ t02, const v2f* __restrict__ t12,
                               v2f Xf2, v2f Yf2, v2f& acc0, v2f& acc1) {
    #pragma unroll 8
    for (int j = 0; j < FT; ++j) {
        v2f v = Xf2 * yg2[j] + Yf2 * xg2[j];          // s(f-pair, g)
        v2f S;
        S.x = copysignf(__builtin_amdgcn_sqrtf(fabsf(v.x)), v.x);
        S.y = copysignf(__builtin_amdgcn_sqrtf(fabsf(v.y)), v.y);
        acc0 += S * t02[j];
        acc1 += S * t12[j];
    }
}

// K3: pass-1 partial matvec with inline denom-reduce + t1 = (w1*x+b1)*rden.
// grid (4, GS, Bn); each thread owns 2 adjacent f, both channels.
__global__ void mv1_partial_kernel(const float* __restrict__ x, const float* __restrict__ ysum,
                                   const float* __restrict__ dpart,
                                   const float* __restrict__ w1, const float* __restrict__ b1,
                                   float* __restrict__ part) {
    __shared__ v2f xg2[FT], yg2[FT], t02[FT], t12[FT];
    const int ftile = blockIdx.x;
    const int gs    = blockIdx.y;
    const int b     = blockIdx.z;
    const int tid   = threadIdx.x;
    const float* xb = x + (size_t)b * Fn;
    const float* yb = ysum + (size_t)b * Fn;
    {
        int g = gs * FT + tid;
        float d = 0.f;
        #pragma unroll
        for (int fs = 0; fs < GS; ++fs) d += dpart[((size_t)fs * Bn + b) * Fn + g];
        float r = 1.0f / (d + 1e-7f);
        float xg = xb[g], yg = yb[g];
        float t0 = fmaf(w1[0], xg, b1[0]) * r;
        float t1 = fmaf(w1[1], xg, b1[1]) * r;
        xg2[tid] = (v2f){xg, xg};
        yg2[tid] = (v2f){yg, yg};
        t02[tid] = (v2f){t0, t0};
        t12[tid] = (v2f){t1, t1};
    }
    const int fbase = (ftile * NT + tid) * 2;
    const v2f Xf2 = *(const v2f*)(xb + fbase);
    const v2f Yf2 = *(const v2f*)(yb + fbase);
    __syncthreads();
    v2f acc0 = (v2f){0.f, 0.f}, acc1 = (v2f){0.f, 0.f};
    mv_loop(xg2, yg2, t02, t12, Xf2, Yf2, acc0, acc1);
    size_t base = (((size_t)gs * Bn + b) * HIDn) * Fn;
    *(v2f*)(part + base + fbase)      = acc0;
    *(v2f*)(part + base + Fn + fbase) = acc1;
}

// K5: pass-2 partial matvec with inline BN1 + softsign + w2 + rden recompute.
__global__ void mv2_partial_kernel(const float* __restrict__ x, const float* __restrict__ ysum,
                                   const float* __restrict__ dpart, const float* __restrict__ out1,
                                   const double* __restrict__ stats,
                                   const float* __restrict__ g1, const float* __restrict__ beta1,
                                   const float* __restrict__ w2, const float* __restrict__ b2,
                                   float* __restrict__ part) {
    __shared__ v2f xg2[FT], yg2[FT], t02[FT], t12[FT];
    const int ftile = blockIdx.x;
    const int gs    = blockIdx.y;
    const int b     = blockIdx.z;
    const int tid   = threadIdx.x;
    const float* xb = x + (size_t)b * Fn;
    const float* yb = ysum + (size_t)b * Fn;
    {
        const double N = (double)(Bn * Fn);
        double m0d = stats[0] / N, m1d = stats[1] / N;
        float mean0 = (float)m0d, mean1 = (float)m1d;
        float var0 = (float)(stats[2] / N - m0d * m0d);
        float var1 = (float)(stats[3] / N - m1d * m1d);
        float inv0 = rsqrtf(var0 + EPSn) * g1[0];
        float inv1 = rsqrtf(var1 + EPSn) * g1[1];
        int g = gs * FT + tid;
        float d = 0.f;
        #pragma unroll
        for (int fs = 0; fs < GS; ++fs) d += dpart[((size_t)fs * Bn + b) * Fn + g];
        float r = 1.0f / (d + 1e-7f);
        size_t obase = ((size_t)b * HIDn) * Fn + g;
        float o0 = out1[obase], o1 = out1[obase + Fn];
        float y0 = fmaf(o0 - mean0, inv0, beta1[0]);
        float y1 = fmaf(o1 - mean1, inv1, beta1[1]);
        float z0 = y0 / (1.f + fabsf(y0));
        float z1 = y1 / (1.f + fabsf(y1));
        float t0 = fmaf(w2[0], z0, fmaf(w2[1], z1, b2[0])) * r;
        float t1 = fmaf(w2[2], z0, fmaf(w2[3], z1, b2[1])) * r;
        float xg = xb[g], yg = yb[g];
        xg2[tid] = (v2f){xg, xg};
        yg2[tid] = (v2f){yg, yg};
        t02[tid] = (v2f){t0, t0};
        t12[tid] = (v2f){t1, t1};
    }
    const int fbase = (ftile * NT + tid) * 2;
    const v2f Xf2 = *(const v2f*)(xb + fbase);
    const v2f Yf2 = *(const v2f*)(yb + fbase);
    __syncthreads();
    v2f acc0 = (v2f){0.f, 0.f}, acc1 = (v2f){0.f, 0.f};
    mv_loop(xg2, yg2, t02, t12, Xf2, Yf2, acc0, acc1);
    size_t base = (((size_t)gs * Bn + b) * HIDn) * Fn;
    *(v2f*)(part + base + fbase)      = acc0;
    *(v2f*)(part + base + Fn + fbase) = acc1;
}

// ---------------------------------------------------------------------------
// K4/K6: reduce matvec partials -> out[b,c,f], plus BN statistics.
// grid (B*F/2/NT = 128, NT); each thread reduces one adjacent f-pair, both ch.
__global__ void mv_reduce_kernel(const float* __restrict__ part, float* __restrict__ out,
                                 double* __restrict__ stats) {
    __shared__ float red[4][4];
    int pidx = blockIdx.x * NT + threadIdx.x;         // over B*F/2 pairs
    int b = pidx >> 10;                               // 1024 pairs per b
    int fp = pidx & 1023;
    const size_t stride = (size_t)Bn * HIDn * Fn;
    size_t base = ((size_t)b * HIDn) * Fn + fp * 2;
    v2f o0 = (v2f){0.f, 0.f}, o1 = (v2f){0.f, 0.f};
    #pragma unroll
    for (int gs = 0; gs < GS; ++gs) {
        v2f p0 = *(const v2f*)(part + (size_t)gs * stride + base);
        v2f p1 = *(const v2f*)(part + (size_t)gs * stride + base + Fn);
        o0 += p0;
        o1 += p1;
    }
    *(v2f*)(out + base)      = o0;
    *(v2f*)(out + base + Fn) = o1;
    float s0 = wave_sum(o0.x + o0.y);
    float s1 = wave_sum(o1.x + o1.y);
    float q0 = wave_sum(o0.x * o0.x + o0.y * o0.y);
    float q1 = wave_sum(o1.x * o1.x + o1.y * o1.y);
    int wid = threadIdx.x >> 6, lane = threadIdx.x & 63;
    if (lane == 0) { red[wid][0] = s0; red[wid][1] = s1; red[wid][2] = q0; red[wid][3] = q1; }
    __syncthreads();
    if (threadIdx.x == 0) {
        double S0 = 0, S1 = 0, Q0 = 0, Q1 = 0;
        #pragma unroll
        for (int w = 0; w < 4; ++w) {
            S0 += red[w][0]; S1 += red[w][1]; Q0 += red[w][2]; Q1 += red[w][3];
        }
        atomicAdd(&stats[0], S0);
        atomicAdd(&stats[1], S1);
        atomicAdd(&stats[2], Q0);
        atomicAdd(&stats[3], Q1);
    }
}

// ---------------------------------------------------------------------------
// K7: fused BN2 + softsign (into LDS) + classifier. grid (NCLS, B).
__global__ void classifier_kernel(const float* __restrict__ out2, const double* __restrict__ stats,
                                  const float* __restrict__ g2, const float* __restrict__ beta2,
                                  const float* __restrict__ Wc, const float* __restrict__ bc,
                                  float* __restrict__ out) {
    __shared__ float z[HIDn * Fn];  // 16 KiB
    const int n = blockIdx.x;
    const int b = blockIdx.y;
    const double N = (double)(Bn * Fn);
    double m0d = stats[0] / N, m1d = stats[1] / N;
    float mean0 = (float)m0d, mean1 = (float)m1d;
    float var0 = (float)(stats[2] / N - m0d * m0d);
    float var1 = (float)(stats[3] / N - m1d * m1d);
    float inv0 = rsqrtf(var0 + EPSn) * g2[0];
    float inv1 = rsqrtf(var1 + EPSn) * g2[1];
    float bet0 = beta2[0], bet1 = beta2[1];
    const float* src = out2 + (size_t)b * HIDn * Fn;
    #pragma unroll
    for (int it = 0; it < (HIDn * Fn) / NT; ++it) {
        int i = it * NT + threadIdx.x;
        int c = i >> 11;
        float v = src[i];
        float y = fmaf(v - (c ? mean1 : mean0), (c ? inv1 : inv0), (c ? bet1 : bet0));
        z[i] = y / (1.f + fabsf(y));
    }
    __syncthreads();
    const float4* z4 = (const float4*)z;
    const float4* w4 = (const float4*)(Wc + (size_t)n * (HIDn * Fn));
    float acc = 0.f;
    #pragma unroll
    for (int it = 0; it < (HIDn * Fn) / (4 * NT); ++it) {
        int i = it * NT + threadIdx.x;
        float4 a = z4[i];
        float4 w = w4[i];
        acc = fmaf(a.x, w.x, acc);
        acc = fmaf(a.y, w.y, acc);
        acc = fmaf(a.z, w.z, acc);
        acc = fmaf(a.w, w.w, acc);
    }
    __shared__ float red[4];
    float s = wave_sum(acc);
    int wid = threadIdx.x >> 6, lane = threadIdx.x & 63;
    if (lane == 0) red[wid] = s;
    __syncthreads();
    if (threadIdx.x == 0) {
        float tot = (red[0] + red[1]) + (red[2] + red[3]);
        out[(size_t)b * NCLSn + n] = tot + bc[n];
    }
}

} // namespace

extern "C" void kernel_launch(void* const* d_in, const int* in_sizes, int n_in,
                              void* d_out, int out_size, void* d_ws, size_t ws_size,
                              hipStream_t stream) {
    const float* x        = (const float*)d_in[0];
    const float* neighbor = (const float*)d_in[1];
    const float* w1       = (const float*)d_in[2];
    const float* b1       = (const float*)d_in[3];
    const float* g1       = (const float*)d_in[4];
    const float* beta1    = (const float*)d_in[5];
    const float* w2       = (const float*)d_in[6];
    const float* b2       = (const float*)d_in[7];
    const float* g2       = (const float*)d_in[8];
    const float* beta2    = (const float*)d_in[9];
    const float* Wc       = (const float*)d_in[10];
    const float* bc       = (const float*)d_in[11];
    float* out = (float*)d_out;

    float* ws    = (float*)d_ws;
    float* ysum  = ws;                        // B*F
    float* dpart = ysum + Bn * Fn;            // GS*B*F
    float* part  = dpart + (size_t)GS * Bn * Fn;        // GS*B*HID*F
    float* out1  = part + (size_t)GS * Bn * HIDn * Fn;  // B*HID*F
    float* out2  = out1 + Bn * HIDn * Fn;     // B*HID*F
    double* stats = (double*)(out2 + Bn * HIDn * Fn);   // 8 doubles

    const dim3 grid_split(Fn / (NT * 2), GS, Bn);  // (4, 8, 32) = 1024 blocks

    ysum_kernel<<<(Bn * Fn) / NT, NT, 0, stream>>>(neighbor, ysum, stats);
    denom_partial_kernel<<<grid_split, NT, 0, stream>>>(x, ysum, dpart);
    mv1_partial_kernel<<<grid_split, NT, 0, stream>>>(x, ysum, dpart, w1, b1, part);
    mv_reduce_kernel<<<(Bn * Fn / 2) / NT, NT, 0, stream>>>(part, out1, stats);
    mv2_partial_kernel<<<grid_split, NT, 0, stream>>>(x, ysum, dpart, out1, stats, g1, beta1, w2, b2, part);
    mv_reduce_kernel<<<(Bn * Fn / 2) / NT, NT, 0, stream>>>(part, out2, stats + 4);
    classifier_kernel<<<dim3(NCLSn, Bn), NT, 0, stream>>>(out2, stats + 4, g2, beta2, Wc, bc, out);
}